// Round 22
// baseline (141.055 us; speedup 1.0000x reference)
//
#include <hip/hip_runtime.h>
#include <hip/hip_bf16.h>
#include <math.h>

#define N_PTS 200000
#define M 32
#define P_INST 64
#define D 16
#define NP 337

#define NBL ((N_PTS + 255) / 256)      // 782 layer blocks (256 pts each)
#define HPB 128                        // points per head block
#define NBH ((N_PTS + HPB - 1) / HPB)  // 1563

// ws float-offset layout:
#define WS_PARAMS 0         // 64*337 = 21568
#define WS_STATS  21568     // 3*64 (per layer: a[32], c[32])
#define WS_W2     21760     // 64*16
#define WS_B2     22784     // 64
#define WS_APACK  22912     // 32 p_pairs * 2048B = 64KB = 16384 float-slots
#define WS_Y      104832    // 200000*32 floats (25.6MB)
// partials[NBL][64] live in d_out (scratch until k_head overwrites)

typedef __attribute__((ext_vector_type(8))) short short8v;
typedef __attribute__((ext_vector_type(4))) float floatx4;
typedef __attribute__((ext_vector_type(16))) float floatx16;

static __device__ __forceinline__ unsigned short f2bf(float v) {
    __hip_bfloat16 h = __float2bfloat16(v);
    return *reinterpret_cast<unsigned short*>(&h);
}

// ---------------------------------------------------------------------------
// k_prep (R12/R16-verified, unchanged)
// ---------------------------------------------------------------------------
__global__ __launch_bounds__(1024) void k_prep(
    const float* __restrict__ inst, const float* __restrict__ emb_w,
    const float* __restrict__ emb_g, const float* __restrict__ emb_b,
    const float* __restrict__ ctrl_w, const float* __restrict__ ctrl_b,
    const float* __restrict__ centers,
    float* __restrict__ params, float* __restrict__ apackf,
    float* __restrict__ w2p, float* __restrict__ b2p)
{
    __shared__ float sInst[P_INST * M];
    __shared__ float sCW[D * NP];
    __shared__ float sE[P_INST * D];
    __shared__ float sA[D], sC[D];
    int t = threadIdx.x;
    int lane = t & 63, wv = t >> 6;

    for (int i = t; i < P_INST * M; i += 1024) sInst[i] = inst[i];
    for (int i = t; i < D * NP; i += 1024) sCW[i] = ctrl_w[i];
    __syncthreads();

    {
        int p = t >> 4, d = t & (D - 1);
        float acc = 0.f;
        #pragma unroll
        for (int k = 0; k < M; k++) acc = fmaf(sInst[p * M + k], emb_w[k * D + d], acc);
        sE[t] = acc;
    }
    __syncthreads();

    if (t < D) {
        float s = 0.f, q = 0.f;
        for (int p = 0; p < P_INST; p++) { float v = sE[p * D + t]; s += v; q += v * v; }
        float mu = s * (1.f / P_INST);
        float var = q * (1.f / P_INST) - mu * mu;
        float a = emb_g[t] * rsqrtf(var + 1e-5f);
        sA[t] = a;
        sC[t] = emb_b[t] - mu * a;
    }
    __syncthreads();

    {
        int d = t & (D - 1);
        sE[t] = fmaxf(sE[t] * sA[d] + sC[d], 0.f);
    }
    __syncthreads();

    #pragma unroll
    for (int pp = 0; pp < 4; pp++) {
        int p = wv * 4 + pp;
        float e[D];
        #pragma unroll
        for (int d = 0; d < D; d++) e[d] = sE[p * D + d];
        for (int q = lane; q < NP; q += 64) {
            float acc = ctrl_b[q];
            #pragma unroll
            for (int d = 0; d < D; d++) acc = fmaf(e[d], sCW[d * NP + q], acc);
            params[p * NP + q] = acc;
        }
    }
    __threadfence_block();
    __syncthreads();

    {
        int row = lane & 31;            // p_sub*16 + d
        int d = row & 15, psub = row >> 4;
        #pragma unroll
        for (int half = 0; half < 2; half++) {
            int pp = wv + half * 16;
            int p = pp * 2 + psub;
            const float* prm = params + p * NP;
            float bias = prm[320 + d] - (centers[p * 3 + 0] * prm[d * 19 + 0]
                                       + centers[p * 3 + 1] * prm[d * 19 + 1]
                                       + centers[p * 3 + 2] * prm[d * 19 + 2]);
            #pragma unroll
            for (int kc = 0; kc < 2; kc++) {
                int kbase = kc * 16 + (lane >> 5) * 8;
                unsigned int w[4];
                #pragma unroll
                for (int i = 0; i < 4; i++) {
                    unsigned short lo = 0, hi = 0;
                    #pragma unroll
                    for (int h = 0; h < 2; h++) {
                        int k = kbase + 2 * i + h;
                        float v;
                        if (k < 19) v = prm[d * 19 + k];
                        else if (k == 19) v = bias;
                        else v = 0.f;
                        if (h == 0) lo = f2bf(v); else hi = f2bf(v);
                    }
                    w[i] = (unsigned)lo | ((unsigned)hi << 16);
                }
                uint4* dst = (uint4*)((char*)apackf + (size_t)pp * 2048
                                      + kc * 1024 + lane * 16);
                *dst = make_uint4(w[0], w[1], w[2], w[3]);
            }
        }
    }

    {
        #pragma unroll
        for (int pi = 0; pi < 4; pi++) {
            int p = wv + pi * 16;
            const float* prm = params + p * NP;
            if (lane < 16) w2p[p * 16 + lane] = prm[304 + lane];
            if (lane == 0) b2p[p] = prm[336];
        }
    }
}

// ---------------------------------------------------------------------------
// MLP layer + fused stats (R16-verified, unchanged)
// ---------------------------------------------------------------------------
template <int L>
__global__ __launch_bounds__(256) void k_layer(
    const float* __restrict__ feats, const float* __restrict__ W,
    const float* __restrict__ stats, float* __restrict__ ybuf,
    float* __restrict__ partials)
{
    __shared__ float tr[256 * 33];
    __shared__ float red2[2][8][32];
    int t = threadIdx.x;
    int n = blockIdx.x * 256 + t;
    bool valid = n < N_PTS;
    int nc = valid ? n : N_PTS - 1;

    const float* src = ((L == 0) ? feats : ybuf) + (size_t)nc * M;
    float x[M];
    #pragma unroll
    for (int q = 0; q < M / 4; q++) {
        float4 v = ((const float4*)src)[q];
        x[4*q] = v.x; x[4*q+1] = v.y; x[4*q+2] = v.z; x[4*q+3] = v.w;
    }
    if (L > 0) {
        const float* st = stats + (L - 1) * 64;
        #pragma unroll
        for (int j = 0; j < M; j++) x[j] = fmaxf(fmaf(x[j], st[j], st[32 + j]), 0.f);
    }
    float y[M];
    #pragma unroll
    for (int j = 0; j < M; j++) y[j] = 0.f;
    #pragma unroll
    for (int i = 0; i < M; i++) {
        float xi = x[i];
        #pragma unroll
        for (int j = 0; j < M; j++) y[j] = fmaf(xi, W[i * M + j], y[j]);
    }
    if (valid) {
        float4* dst = (float4*)(ybuf + (size_t)n * M);
        #pragma unroll
        for (int q = 0; q < M / 4; q++)
            dst[q] = make_float4(y[4*q], y[4*q+1], y[4*q+2], y[4*q+3]);
    } else {
        #pragma unroll
        for (int j = 0; j < M; j++) y[j] = 0.f;
    }

    #pragma unroll
    for (int j = 0; j < M; j++) tr[t * 33 + j] = y[j];
    __syncthreads();
    int c = t & 31, s = t >> 5;
    float S = 0.f, Q = 0.f;
    #pragma unroll
    for (int r = 0; r < 32; r++) {
        float v = tr[(s * 32 + r) * 33 + c];
        S += v; Q += v * v;
    }
    red2[0][s][c] = S;
    red2[1][s][c] = Q;
    __syncthreads();
    if (t < 64) {
        int cc = t & 31, k = t >> 5;
        float a = 0.f;
        #pragma unroll
        for (int sl = 0; sl < 8; sl++) a += red2[k][sl][cc];
        partials[(size_t)blockIdx.x * 64 + k * 32 + cc] = a;
    }
}

// ---------------------------------------------------------------------------
// Parallel reduce (R16-verified, unchanged)
// ---------------------------------------------------------------------------
__global__ __launch_bounds__(256) void k_reduce(
    const float* __restrict__ partials,
    const float* __restrict__ g, const float* __restrict__ b,
    float* __restrict__ stats_out)
{
    int c = blockIdx.x;
    int t = threadIdx.x;
    int part = t >> 7;
    int i0 = t & 127;
    float s = 0.f;
    for (int i = i0; i < NBL; i += 128)
        s += partials[(size_t)i * 64 + part * 32 + c];
    __shared__ float sh[256];
    sh[t] = s;
    __syncthreads();
    #pragma unroll
    for (int off = 64; off; off >>= 1) {
        if ((t & 127) < off) sh[t] += sh[t + off];
        __syncthreads();
    }
    if (t == 0) {
        float S = sh[0], Q = sh[128];
        float mu = S * (1.f / N_PTS);
        float var = Q * (1.f / N_PTS) - mu * mu;
        float a = g[c] * rsqrtf(var + 1e-5f);
        stats_out[c] = a;
        stats_out[32 + c] = b[c] - mu * a;
    }
}

// ---------------------------------------------------------------------------
// Fused head — R16 structure exactly; R22 single change:
// amdgpu_waves_per_eu(4) forces the RA to a 128-reg (VGPR+AGPR) budget so
// 4 waves/SIMD fit (true footprint ~110-130 regs was landing at 2-3 waves).
// R15 showed min=8 (64-reg budget) spills; 128 should not.
// ---------------------------------------------------------------------------
__global__ __launch_bounds__(512)
__attribute__((amdgpu_waves_per_eu(4)))
void k_head(
    const float* __restrict__ ybuf, const float* __restrict__ coords,
    const float* __restrict__ w_out, const float* __restrict__ b_out,
    const float* __restrict__ stats, const float* __restrict__ w2p,
    const float* __restrict__ b2p, const float* __restrict__ apackf,
    float* __restrict__ out)
{
    __shared__ unsigned int zlds[HPB * 20];   // 80B stride per point
    __shared__ float w2lds[32 * 32];          // [pp][hi*16 + reg]
    __shared__ float b2lds[64];
    int t = threadIdx.x;
    int nblk = blockIdx.x * HPB;

    // ---- phase 1 ----
    if (t < HPB) {
        int nc = nblk + t;
        if (nc >= N_PTS) nc = N_PTS - 1;
        const float* yr = ybuf + (size_t)nc * M;
        float x[M];
        #pragma unroll
        for (int q = 0; q < M / 4; q++) {
            float4 v = ((const float4*)yr)[q];
            x[4*q] = v.x; x[4*q+1] = v.y; x[4*q+2] = v.z; x[4*q+3] = v.w;
        }
        const float* st = stats + 128;
        #pragma unroll
        for (int j = 0; j < M; j++) x[j] = fmaxf(fmaf(x[j], st[j], st[32 + j]), 0.f);

        float mf[D];
        #pragma unroll
        for (int d = 0; d < D; d++) mf[d] = b_out[d];
        #pragma unroll
        for (int i = 0; i < M; i++) {
            float xi = x[i];
            #pragma unroll
            for (int d = 0; d < D; d++) mf[d] = fmaf(xi, w_out[i * D + d], mf[d]);
        }
        float z[20];
        z[0] = coords[(size_t)nc * 3 + 0];
        z[1] = coords[(size_t)nc * 3 + 1];
        z[2] = coords[(size_t)nc * 3 + 2];
        #pragma unroll
        for (int d = 0; d < D; d++) z[3 + d] = mf[d];
        z[19] = 1.0f;

        unsigned int zw[16];
        #pragma unroll
        for (int i = 0; i < 10; i++)
            zw[i] = (unsigned)f2bf(z[2 * i]) | ((unsigned)f2bf(z[2 * i + 1]) << 16);
        #pragma unroll
        for (int i = 10; i < 16; i++) zw[i] = 0u;
        uint4* zd = (uint4*)&zlds[t * 20];
        #pragma unroll
        for (int i = 0; i < 4; i++)
            zd[i] = make_uint4(zw[4*i], zw[4*i+1], zw[4*i+2], zw[4*i+3]);
    } else if (t < 256) {
        int t2 = t - 128;
        if (t2 < 64) b2lds[t2] = b2p[t2];
        #pragma unroll
        for (int e = 0; e < 8; e++) {
            int idx = t2 * 8 + e;
            int pp = idx >> 5;
            int rem = idx & 31;
            int hi = rem >> 4, reg = rem & 15;
            int R = (reg & 3) + 8 * (reg >> 2) + 4 * hi;   // acc row
            int p = pp * 2 + (R >> 4), d = R & 15;
            w2lds[idx] = w2p[p * 16 + d];
        }
    }
    __syncthreads();

    // ---- phase 2 ----
    int lane = t & 63, wv = t >> 6;       // wv owns pp = wv*4 .. wv*4+3
    int col = lane & 31, hi = lane >> 5;

    short8v B1[4], B2[4];
    #pragma unroll
    for (int s = 0; s < 4; s++) {
        const unsigned int* zrow = &zlds[(s * 32 + col) * 20];
        B1[s] = *(const short8v*)(zrow + hi * 4);
        B2[s] = *(const short8v*)(zrow + 8 + hi * 4);
    }

    const char* abase = (const char*)apackf + (size_t)(wv * 4) * 2048 + lane * 16;

    short8v A1n = *(const short8v*)(abase);
    short8v A2n = *(const short8v*)(abase + 1024);

    #pragma unroll
    for (int i = 0; i < 4; i++) {
        int pp = wv * 4 + i;
        short8v A1 = A1n, A2 = A2n;
        if (i < 3) {
            A1n = *(const short8v*)(abase + (size_t)(i + 1) * 2048);
            A2n = *(const short8v*)(abase + (size_t)(i + 1) * 2048 + 1024);
        }
        const float* w2r = &w2lds[pp * 32 + hi * 16];
        floatx4 w2a = *(const floatx4*)(w2r + 0);
        floatx4 w2b = *(const floatx4*)(w2r + 4);
        floatx4 w2c = *(const floatx4*)(w2r + 8);
        floatx4 w2d = *(const floatx4*)(w2r + 12);
        float b2 = b2lds[pp * 2 + hi];

        #pragma unroll
        for (int s = 0; s < 4; s++) {
            floatx16 acc = {};
            acc = __builtin_amdgcn_mfma_f32_32x32x16_bf16(A1, B1[s], acc, 0, 0, 0);
            acc = __builtin_amdgcn_mfma_f32_32x32x16_bf16(A2, B2[s], acc, 0, 0, 0);

            float pA = fmaxf(acc[0], 0.f) * w2a[0];
            pA = fmaf(fmaxf(acc[1], 0.f), w2a[1], pA);
            pA = fmaf(fmaxf(acc[2], 0.f), w2a[2], pA);
            pA = fmaf(fmaxf(acc[3], 0.f), w2a[3], pA);
            pA = fmaf(fmaxf(acc[4], 0.f), w2b[0], pA);
            pA = fmaf(fmaxf(acc[5], 0.f), w2b[1], pA);
            pA = fmaf(fmaxf(acc[6], 0.f), w2b[2], pA);
            pA = fmaf(fmaxf(acc[7], 0.f), w2b[3], pA);
            float pB = fmaxf(acc[8], 0.f) * w2c[0];
            pB = fmaf(fmaxf(acc[9], 0.f), w2c[1], pB);
            pB = fmaf(fmaxf(acc[10], 0.f), w2c[2], pB);
            pB = fmaf(fmaxf(acc[11], 0.f), w2c[3], pB);
            pB = fmaf(fmaxf(acc[12], 0.f), w2d[0], pB);
            pB = fmaf(fmaxf(acc[13], 0.f), w2d[1], pB);
            pB = fmaf(fmaxf(acc[14], 0.f), w2d[2], pB);
            pB = fmaf(fmaxf(acc[15], 0.f), w2d[3], pB);

            pA += __shfl_xor(pA, 32, 64);
            pB += __shfl_xor(pB, 32, 64);

            int nn = nblk + s * 32 + col;
            float vout = (hi ? pB : pA) + b2;
            if (nn < N_PTS) out[(size_t)(pp * 2 + hi) * N_PTS + nn] = vout;
        }
    }
}

// ---------------------------------------------------------------------------
extern "C" void kernel_launch(void* const* d_in, const int* in_sizes, int n_in,
                              void* d_out, int out_size, void* d_ws, size_t ws_size,
                              hipStream_t stream) {
    const float* feats   = (const float*)d_in[0];
    const float* coords  = (const float*)d_in[1];
    const float* inst    = (const float*)d_in[2];
    const float* centers = (const float*)d_in[3];
    const float* mw1 = (const float*)d_in[4];
    const float* mg1 = (const float*)d_in[5];
    const float* mb1 = (const float*)d_in[6];
    const float* mw2 = (const float*)d_in[7];
    const float* mg2 = (const float*)d_in[8];
    const float* mb2 = (const float*)d_in[9];
    const float* mw3 = (const float*)d_in[10];
    const float* mg3 = (const float*)d_in[11];
    const float* mb3 = (const float*)d_in[12];
    const float* wout = (const float*)d_in[13];
    const float* bout = (const float*)d_in[14];
    const float* embw = (const float*)d_in[15];
    const float* embg = (const float*)d_in[16];
    const float* embb = (const float*)d_in[17];
    const float* cw   = (const float*)d_in[18];
    const float* cb   = (const float*)d_in[19];

    float* wsf      = (float*)d_ws;
    float* params   = wsf + WS_PARAMS;
    float* stats    = wsf + WS_STATS;
    float* w2p      = wsf + WS_W2;
    float* b2p      = wsf + WS_B2;
    float* apackf   = wsf + WS_APACK;
    float* ybuf     = wsf + WS_Y;
    float* out      = (float*)d_out;
    float* partials = (float*)d_out;   // scratch until k_head overwrites out

    k_prep<<<1, 1024, 0, stream>>>(inst, embw, embg, embb, cw, cb, centers,
                                   params, apackf, w2p, b2p);

    k_layer<0><<<NBL, 256, 0, stream>>>(feats, mw1, stats, ybuf, partials);
    k_reduce<<<32, 256, 0, stream>>>(partials, mg1, mb1, stats + 0);

    k_layer<1><<<NBL, 256, 0, stream>>>(feats, mw2, stats, ybuf, partials);
    k_reduce<<<32, 256, 0, stream>>>(partials, mg2, mb2, stats + 64);

    k_layer<2><<<NBL, 256, 0, stream>>>(feats, mw3, stats, ybuf, partials);
    k_reduce<<<32, 256, 0, stream>>>(partials, mg3, mb3, stats + 128);

    k_head<<<NBH, 512, 0, stream>>>(ybuf, coords, wout, bout, stats,
                                    w2p, b2p, apackf, out);
}

// Round 23
// 139.666 us; speedup vs baseline: 1.0099x; 1.0099x over previous
//
#include <hip/hip_runtime.h>
#include <hip/hip_bf16.h>
#include <math.h>

#define N_PTS 200000
#define M 32
#define P_INST 64
#define D 16
#define NP 337

#define NBL ((N_PTS + 255) / 256)      // 782 layer blocks (256 pts each)
#define HPB 128                        // points per head block
#define NBH ((N_PTS + HPB - 1) / HPB)  // 1563

// ws float-offset layout:
#define WS_PARAMS 0         // 64*337 = 21568
#define WS_STATS  21568     // 3*64 (per layer: a[32], c[32])
#define WS_W2     21760     // 64*16
#define WS_B2     22784     // 64
#define WS_APACK  22912     // 32 p_pairs * 2048B = 64KB = 16384 float-slots
#define WS_Y      104832    // 200000*32 floats (25.6MB)
// partials[NBL][64] live in d_out (scratch until k_head overwrites)

typedef __attribute__((ext_vector_type(8))) short short8v;
typedef __attribute__((ext_vector_type(4))) float floatx4;
typedef __attribute__((ext_vector_type(16))) float floatx16;

static __device__ __forceinline__ unsigned short f2bf(float v) {
    __hip_bfloat16 h = __float2bfloat16(v);
    return *reinterpret_cast<unsigned short*>(&h);
}

// ---------------------------------------------------------------------------
// k_prep (R12/R16-verified)
// ---------------------------------------------------------------------------
__global__ __launch_bounds__(1024) void k_prep(
    const float* __restrict__ inst, const float* __restrict__ emb_w,
    const float* __restrict__ emb_g, const float* __restrict__ emb_b,
    const float* __restrict__ ctrl_w, const float* __restrict__ ctrl_b,
    const float* __restrict__ centers,
    float* __restrict__ params, float* __restrict__ apackf,
    float* __restrict__ w2p, float* __restrict__ b2p)
{
    __shared__ float sInst[P_INST * M];
    __shared__ float sCW[D * NP];
    __shared__ float sE[P_INST * D];
    __shared__ float sA[D], sC[D];
    int t = threadIdx.x;
    int lane = t & 63, wv = t >> 6;

    for (int i = t; i < P_INST * M; i += 1024) sInst[i] = inst[i];
    for (int i = t; i < D * NP; i += 1024) sCW[i] = ctrl_w[i];
    __syncthreads();

    {
        int p = t >> 4, d = t & (D - 1);
        float acc = 0.f;
        #pragma unroll
        for (int k = 0; k < M; k++) acc = fmaf(sInst[p * M + k], emb_w[k * D + d], acc);
        sE[t] = acc;
    }
    __syncthreads();

    if (t < D) {
        float s = 0.f, q = 0.f;
        for (int p = 0; p < P_INST; p++) { float v = sE[p * D + t]; s += v; q += v * v; }
        float mu = s * (1.f / P_INST);
        float var = q * (1.f / P_INST) - mu * mu;
        float a = emb_g[t] * rsqrtf(var + 1e-5f);
        sA[t] = a;
        sC[t] = emb_b[t] - mu * a;
    }
    __syncthreads();

    {
        int d = t & (D - 1);
        sE[t] = fmaxf(sE[t] * sA[d] + sC[d], 0.f);
    }
    __syncthreads();

    #pragma unroll
    for (int pp = 0; pp < 4; pp++) {
        int p = wv * 4 + pp;
        float e[D];
        #pragma unroll
        for (int d = 0; d < D; d++) e[d] = sE[p * D + d];
        for (int q = lane; q < NP; q += 64) {
            float acc = ctrl_b[q];
            #pragma unroll
            for (int d = 0; d < D; d++) acc = fmaf(e[d], sCW[d * NP + q], acc);
            params[p * NP + q] = acc;
        }
    }
    __threadfence_block();
    __syncthreads();

    {
        int row = lane & 31;            // p_sub*16 + d
        int d = row & 15, psub = row >> 4;
        #pragma unroll
        for (int half = 0; half < 2; half++) {
            int pp = wv + half * 16;
            int p = pp * 2 + psub;
            const float* prm = params + p * NP;
            float bias = prm[320 + d] - (centers[p * 3 + 0] * prm[d * 19 + 0]
                                       + centers[p * 3 + 1] * prm[d * 19 + 1]
                                       + centers[p * 3 + 2] * prm[d * 19 + 2]);
            #pragma unroll
            for (int kc = 0; kc < 2; kc++) {
                int kbase = kc * 16 + (lane >> 5) * 8;
                unsigned int w[4];
                #pragma unroll
                for (int i = 0; i < 4; i++) {
                    unsigned short lo = 0, hi = 0;
                    #pragma unroll
                    for (int h = 0; h < 2; h++) {
                        int k = kbase + 2 * i + h;
                        float v;
                        if (k < 19) v = prm[d * 19 + k];
                        else if (k == 19) v = bias;
                        else v = 0.f;
                        if (h == 0) lo = f2bf(v); else hi = f2bf(v);
                    }
                    w[i] = (unsigned)lo | ((unsigned)hi << 16);
                }
                uint4* dst = (uint4*)((char*)apackf + (size_t)pp * 2048
                                      + kc * 1024 + lane * 16);
                *dst = make_uint4(w[0], w[1], w[2], w[3]);
            }
        }
    }

    {
        #pragma unroll
        for (int pi = 0; pi < 4; pi++) {
            int p = wv + pi * 16;
            const float* prm = params + p * NP;
            if (lane < 16) w2p[p * 16 + lane] = prm[304 + lane];
            if (lane == 0) b2p[p] = prm[336];
        }
    }
}

// ---------------------------------------------------------------------------
// MLP layer + fused stats (R16-verified)
// ---------------------------------------------------------------------------
template <int L>
__global__ __launch_bounds__(256) void k_layer(
    const float* __restrict__ feats, const float* __restrict__ W,
    const float* __restrict__ stats, float* __restrict__ ybuf,
    float* __restrict__ partials)
{
    __shared__ float tr[256 * 33];
    __shared__ float red2[2][8][32];
    int t = threadIdx.x;
    int n = blockIdx.x * 256 + t;
    bool valid = n < N_PTS;
    int nc = valid ? n : N_PTS - 1;

    const float* src = ((L == 0) ? feats : ybuf) + (size_t)nc * M;
    float x[M];
    #pragma unroll
    for (int q = 0; q < M / 4; q++) {
        float4 v = ((const float4*)src)[q];
        x[4*q] = v.x; x[4*q+1] = v.y; x[4*q+2] = v.z; x[4*q+3] = v.w;
    }
    if (L > 0) {
        const float* st = stats + (L - 1) * 64;
        #pragma unroll
        for (int j = 0; j < M; j++) x[j] = fmaxf(fmaf(x[j], st[j], st[32 + j]), 0.f);
    }
    float y[M];
    #pragma unroll
    for (int j = 0; j < M; j++) y[j] = 0.f;
    #pragma unroll
    for (int i = 0; i < M; i++) {
        float xi = x[i];
        #pragma unroll
        for (int j = 0; j < M; j++) y[j] = fmaf(xi, W[i * M + j], y[j]);
    }
    if (valid) {
        float4* dst = (float4*)(ybuf + (size_t)n * M);
        #pragma unroll
        for (int q = 0; q < M / 4; q++)
            dst[q] = make_float4(y[4*q], y[4*q+1], y[4*q+2], y[4*q+3]);
    } else {
        #pragma unroll
        for (int j = 0; j < M; j++) y[j] = 0.f;
    }

    #pragma unroll
    for (int j = 0; j < M; j++) tr[t * 33 + j] = y[j];
    __syncthreads();
    int c = t & 31, s = t >> 5;
    float S = 0.f, Q = 0.f;
    #pragma unroll
    for (int r = 0; r < 32; r++) {
        float v = tr[(s * 32 + r) * 33 + c];
        S += v; Q += v * v;
    }
    red2[0][s][c] = S;
    red2[1][s][c] = Q;
    __syncthreads();
    if (t < 64) {
        int cc = t & 31, k = t >> 5;
        float a = 0.f;
        #pragma unroll
        for (int sl = 0; sl < 8; sl++) a += red2[k][sl][cc];
        partials[(size_t)blockIdx.x * 64 + k * 32 + cc] = a;
    }
}

// ---------------------------------------------------------------------------
// Parallel reduce (R16-verified)
// ---------------------------------------------------------------------------
__global__ __launch_bounds__(256) void k_reduce(
    const float* __restrict__ partials,
    const float* __restrict__ g, const float* __restrict__ b,
    float* __restrict__ stats_out)
{
    int c = blockIdx.x;
    int t = threadIdx.x;
    int part = t >> 7;
    int i0 = t & 127;
    float s = 0.f;
    for (int i = i0; i < NBL; i += 128)
        s += partials[(size_t)i * 64 + part * 32 + c];
    __shared__ float sh[256];
    sh[t] = s;
    __syncthreads();
    #pragma unroll
    for (int off = 64; off; off >>= 1) {
        if ((t & 127) < off) sh[t] += sh[t + off];
        __syncthreads();
    }
    if (t == 0) {
        float S = sh[0], Q = sh[128];
        float mu = S * (1.f / N_PTS);
        float var = Q * (1.f / N_PTS) - mu * mu;
        float a = g[c] * rsqrtf(var + 1e-5f);
        stats_out[c] = a;
        stats_out[32 + c] = b[c] - mu * a;
    }
}

// ---------------------------------------------------------------------------
// Fused head (R16 final: R12 structure, resource-driven occupancy).
// Converged: 11 structural/occupancy variants measured 53-72us; this is the
// best. Latency-bound on the MFMA->fma-chain->shfl dependent chain at the
// ~2.75 waves/SIMD the register footprint allows.
// ---------------------------------------------------------------------------
__global__ __launch_bounds__(512) void k_head(
    const float* __restrict__ ybuf, const float* __restrict__ coords,
    const float* __restrict__ w_out, const float* __restrict__ b_out,
    const float* __restrict__ stats, const float* __restrict__ w2p,
    const float* __restrict__ b2p, const float* __restrict__ apackf,
    float* __restrict__ out)
{
    __shared__ unsigned int zlds[HPB * 20];   // 80B stride per point
    __shared__ float w2lds[32 * 32];          // [pp][hi*16 + reg]
    __shared__ float b2lds[64];
    int t = threadIdx.x;
    int nblk = blockIdx.x * HPB;

    // ---- phase 1 ----
    if (t < HPB) {
        int nc = nblk + t;
        if (nc >= N_PTS) nc = N_PTS - 1;
        const float* yr = ybuf + (size_t)nc * M;
        float x[M];
        #pragma unroll
        for (int q = 0; q < M / 4; q++) {
            float4 v = ((const float4*)yr)[q];
            x[4*q] = v.x; x[4*q+1] = v.y; x[4*q+2] = v.z; x[4*q+3] = v.w;
        }
        const float* st = stats + 128;
        #pragma unroll
        for (int j = 0; j < M; j++) x[j] = fmaxf(fmaf(x[j], st[j], st[32 + j]), 0.f);

        float mf[D];
        #pragma unroll
        for (int d = 0; d < D; d++) mf[d] = b_out[d];
        #pragma unroll
        for (int i = 0; i < M; i++) {
            float xi = x[i];
            #pragma unroll
            for (int d = 0; d < D; d++) mf[d] = fmaf(xi, w_out[i * D + d], mf[d]);
        }
        float z[20];
        z[0] = coords[(size_t)nc * 3 + 0];
        z[1] = coords[(size_t)nc * 3 + 1];
        z[2] = coords[(size_t)nc * 3 + 2];
        #pragma unroll
        for (int d = 0; d < D; d++) z[3 + d] = mf[d];
        z[19] = 1.0f;

        unsigned int zw[16];
        #pragma unroll
        for (int i = 0; i < 10; i++)
            zw[i] = (unsigned)f2bf(z[2 * i]) | ((unsigned)f2bf(z[2 * i + 1]) << 16);
        #pragma unroll
        for (int i = 10; i < 16; i++) zw[i] = 0u;
        uint4* zd = (uint4*)&zlds[t * 20];
        #pragma unroll
        for (int i = 0; i < 4; i++)
            zd[i] = make_uint4(zw[4*i], zw[4*i+1], zw[4*i+2], zw[4*i+3]);
    } else if (t < 256) {
        int t2 = t - 128;
        if (t2 < 64) b2lds[t2] = b2p[t2];
        #pragma unroll
        for (int e = 0; e < 8; e++) {
            int idx = t2 * 8 + e;
            int pp = idx >> 5;
            int rem = idx & 31;
            int hi = rem >> 4, reg = rem & 15;
            int R = (reg & 3) + 8 * (reg >> 2) + 4 * hi;   // acc row
            int p = pp * 2 + (R >> 4), d = R & 15;
            w2lds[idx] = w2p[p * 16 + d];
        }
    }
    __syncthreads();

    // ---- phase 2 ----
    int lane = t & 63, wv = t >> 6;       // wv owns pp = wv*4 .. wv*4+3
    int col = lane & 31, hi = lane >> 5;

    short8v B1[4], B2[4];
    #pragma unroll
    for (int s = 0; s < 4; s++) {
        const unsigned int* zrow = &zlds[(s * 32 + col) * 20];
        B1[s] = *(const short8v*)(zrow + hi * 4);
        B2[s] = *(const short8v*)(zrow + 8 + hi * 4);
    }

    const char* abase = (const char*)apackf + (size_t)(wv * 4) * 2048 + lane * 16;

    short8v A1n = *(const short8v*)(abase);
    short8v A2n = *(const short8v*)(abase + 1024);

    #pragma unroll
    for (int i = 0; i < 4; i++) {
        int pp = wv * 4 + i;
        short8v A1 = A1n, A2 = A2n;
        if (i < 3) {
            A1n = *(const short8v*)(abase + (size_t)(i + 1) * 2048);
            A2n = *(const short8v*)(abase + (size_t)(i + 1) * 2048 + 1024);
        }
        const float* w2r = &w2lds[pp * 32 + hi * 16];
        floatx4 w2a = *(const floatx4*)(w2r + 0);
        floatx4 w2b = *(const floatx4*)(w2r + 4);
        floatx4 w2c = *(const floatx4*)(w2r + 8);
        floatx4 w2d = *(const floatx4*)(w2r + 12);
        float b2 = b2lds[pp * 2 + hi];

        #pragma unroll
        for (int s = 0; s < 4; s++) {
            floatx16 acc = {};
            acc = __builtin_amdgcn_mfma_f32_32x32x16_bf16(A1, B1[s], acc, 0, 0, 0);
            acc = __builtin_amdgcn_mfma_f32_32x32x16_bf16(A2, B2[s], acc, 0, 0, 0);

            float pA = fmaxf(acc[0], 0.f) * w2a[0];
            pA = fmaf(fmaxf(acc[1], 0.f), w2a[1], pA);
            pA = fmaf(fmaxf(acc[2], 0.f), w2a[2], pA);
            pA = fmaf(fmaxf(acc[3], 0.f), w2a[3], pA);
            pA = fmaf(fmaxf(acc[4], 0.f), w2b[0], pA);
            pA = fmaf(fmaxf(acc[5], 0.f), w2b[1], pA);
            pA = fmaf(fmaxf(acc[6], 0.f), w2b[2], pA);
            pA = fmaf(fmaxf(acc[7], 0.f), w2b[3], pA);
            float pB = fmaxf(acc[8], 0.f) * w2c[0];
            pB = fmaf(fmaxf(acc[9], 0.f), w2c[1], pB);
            pB = fmaf(fmaxf(acc[10], 0.f), w2c[2], pB);
            pB = fmaf(fmaxf(acc[11], 0.f), w2c[3], pB);
            pB = fmaf(fmaxf(acc[12], 0.f), w2d[0], pB);
            pB = fmaf(fmaxf(acc[13], 0.f), w2d[1], pB);
            pB = fmaf(fmaxf(acc[14], 0.f), w2d[2], pB);
            pB = fmaf(fmaxf(acc[15], 0.f), w2d[3], pB);

            pA += __shfl_xor(pA, 32, 64);
            pB += __shfl_xor(pB, 32, 64);

            int nn = nblk + s * 32 + col;
            float vout = (hi ? pB : pA) + b2;
            if (nn < N_PTS) out[(size_t)(pp * 2 + hi) * N_PTS + nn] = vout;
        }
    }
}

// ---------------------------------------------------------------------------
extern "C" void kernel_launch(void* const* d_in, const int* in_sizes, int n_in,
                              void* d_out, int out_size, void* d_ws, size_t ws_size,
                              hipStream_t stream) {
    const float* feats   = (const float*)d_in[0];
    const float* coords  = (const float*)d_in[1];
    const float* inst    = (const float*)d_in[2];
    const float* centers = (const float*)d_in[3];
    const float* mw1 = (const float*)d_in[4];
    const float* mg1 = (const float*)d_in[5];
    const float* mb1 = (const float*)d_in[6];
    const float* mw2 = (const float*)d_in[7];
    const float* mg2 = (const float*)d_in[8];
    const float* mb2 = (const float*)d_in[9];
    const float* mw3 = (const float*)d_in[10];
    const float* mg3 = (const float*)d_in[11];
    const float* mb3 = (const float*)d_in[12];
    const float* wout = (const float*)d_in[13];
    const float* bout = (const float*)d_in[14];
    const float* embw = (const float*)d_in[15];
    const float* embg = (const float*)d_in[16];
    const float* embb = (const float*)d_in[17];
    const float* cw   = (const float*)d_in[18];
    const float* cb   = (const float*)d_in[19];

    float* wsf      = (float*)d_ws;
    float* params   = wsf + WS_PARAMS;
    float* stats    = wsf + WS_STATS;
    float* w2p      = wsf + WS_W2;
    float* b2p      = wsf + WS_B2;
    float* apackf   = wsf + WS_APACK;
    float* ybuf     = wsf + WS_Y;
    float* out      = (float*)d_out;
    float* partials = (float*)d_out;   // scratch until k_head overwrites out

    k_prep<<<1, 1024, 0, stream>>>(inst, embw, embg, embb, cw, cb, centers,
                                   params, apackf, w2p, b2p);

    k_layer<0><<<NBL, 256, 0, stream>>>(feats, mw1, stats, ybuf, partials);
    k_reduce<<<32, 256, 0, stream>>>(partials, mg1, mb1, stats + 0);

    k_layer<1><<<NBL, 256, 0, stream>>>(feats, mw2, stats, ybuf, partials);
    k_reduce<<<32, 256, 0, stream>>>(partials, mg2, mb2, stats + 64);

    k_layer<2><<<NBL, 256, 0, stream>>>(feats, mw3, stats, ybuf, partials);
    k_reduce<<<32, 256, 0, stream>>>(partials, mg3, mb3, stats + 128);

    k_head<<<NBH, 512, 0, stream>>>(ybuf, coords, wout, bout, stats,
                                    w2p, b2p, apackf, out);
}